// Round 1
// baseline (1005.807 us; speedup 1.0000x reference)
//
#include <hip/hip_runtime.h>
#include <hip/hip_cooperative_groups.h>
#include <math.h>

namespace cg = cooperative_groups;

#define NROWS 1048576
#define C 64

// ---- fused cooperative config: 1024 blocks * 256 thr = 4 blocks/CU (guaranteed
//      co-resident via __launch_bounds__(256,4) -> VGPR <= 128, LDS ~1KB) ----
#define FGRID 1024
#define FBLOCK 256
#define FRPS ((FGRID * FBLOCK) / 16)   // rows per sweep = 16384
#define FNITER (NROWS / FRPS)          // 64 sweeps

// ---- fallback config (original proven 4-kernel path) ----
#define GRID 4096
#define BLOCK 256
#define GPT ((GRID * BLOCK) / 16)
#define NITER (NROWS / GPT)

constexpr float EPS = 1e-5f;
constexpr float ACOSH_EPS = 1e-7f;

typedef float f4 __attribute__((ext_vector_type(4)));

// ws layout (floats): [0:64] col_sums, [128] d2sum(/16)

// Sum across the 16-lane DPP row via rotate-and-add: 4 VALU ops, no LDS pipe.
__device__ __forceinline__ float row16_sum(float x) {
    x += __int_as_float(__builtin_amdgcn_update_dpp(
        0, __float_as_int(x), 0x121, 0xF, 0xF, true));  // row_ror:1
    x += __int_as_float(__builtin_amdgcn_update_dpp(
        0, __float_as_int(x), 0x122, 0xF, 0xF, true));  // row_ror:2
    x += __int_as_float(__builtin_amdgcn_update_dpp(
        0, __float_as_int(x), 0x124, 0xF, 0xF, true));  // row_ror:4
    x += __int_as_float(__builtin_amdgcn_update_dpp(
        0, __float_as_int(x), 0x128, 0xF, 0xF, true));  // row_ror:8
    return x;
}

// ===================== fused single-launch cooperative kernel =====================
__global__ __launch_bounds__(FBLOCK, 4) void lbn_fused(
    const float* __restrict__ x, const float* __restrict__ gamma,
    const float* __restrict__ beta, float* __restrict__ out,
    float* __restrict__ ws) {
    cg::grid_group gg = cg::this_grid();
    const int tid = threadIdx.x;
    const int g = tid & 15;
    const int gid0 = ((int)blockIdx.x * FBLOCK + tid) >> 4;
    const int wave = tid >> 6, lane = tid & 63;
    __shared__ float lsum[4][64];
    __shared__ float wsum[4];

    // ---------------- pass 1: column sums (cold HBM read; x allocates in L3) ----
    {
        const float* p = x + (size_t)gid0 * C + g * 4;
        float4 a0{0, 0, 0, 0}, a1{0, 0, 0, 0}, a2{0, 0, 0, 0}, a3{0, 0, 0, 0};
        #pragma unroll 2
        for (int k = 0; k < FNITER; k += 4) {
            const float4 v0 = *(const float4*)(p + (size_t)(k + 0) * FRPS * C);
            const float4 v1 = *(const float4*)(p + (size_t)(k + 1) * FRPS * C);
            const float4 v2 = *(const float4*)(p + (size_t)(k + 2) * FRPS * C);
            const float4 v3 = *(const float4*)(p + (size_t)(k + 3) * FRPS * C);
            a0.x += v0.x; a0.y += v0.y; a0.z += v0.z; a0.w += v0.w;
            a1.x += v1.x; a1.y += v1.y; a1.z += v1.z; a1.w += v1.w;
            a2.x += v2.x; a2.y += v2.y; a2.z += v2.z; a2.w += v2.w;
            a3.x += v3.x; a3.y += v3.y; a3.z += v3.z; a3.w += v3.w;
        }
        float4 acc;
        acc.x = (a0.x + a1.x) + (a2.x + a3.x);
        acc.y = (a0.y + a1.y) + (a2.y + a3.y);
        acc.z = (a0.z + a1.z) + (a2.z + a3.z);
        acc.w = (a0.w + a1.w) + (a2.w + a3.w);
        #pragma unroll
        for (int m = 16; m <= 32; m <<= 1) {
            acc.x += __shfl_xor(acc.x, m, 64);
            acc.y += __shfl_xor(acc.y, m, 64);
            acc.z += __shfl_xor(acc.z, m, 64);
            acc.w += __shfl_xor(acc.w, m, 64);
        }
        if (lane < 16) {
            lsum[wave][lane * 4 + 0] = acc.x;
            lsum[wave][lane * 4 + 1] = acc.y;
            lsum[wave][lane * 4 + 2] = acc.z;
            lsum[wave][lane * 4 + 3] = acc.w;
        }
        __syncthreads();
        if (tid < 64) {
            const float s = lsum[0][tid] + lsum[1][tid] + lsum[2][tid] + lsum[3][tid];
            atomicAdd(&ws[tid], s);
        }
    }
    __threadfence();
    gg.sync();

    // ---------------- mu recomputed in-register by every thread (no mu_kernel) ----
    const float invN = 1.0f / (float)NROWS;
    float4 muv;
    float mu0;
    {
        float4 sv = *(const float4*)(ws + g * 4);
        sv.x *= invN; sv.y *= invN; sv.z *= invN; sv.w *= invN;
        float pp = fmaf(sv.y, sv.y, fmaf(sv.z, sv.z, sv.w * sv.w));
        pp = (g == 0) ? fmaf(-sv.x, sv.x, pp) : fmaf(sv.x, sv.x, pp);
        pp = row16_sum(pp);  // <s,s>_L broadcast to all lanes
        const float sn = sqrtf(fmaxf(-pp, 1e-9f));
        const float inv_sn = 1.0f / sn;
        muv.x = sv.x * inv_sn; muv.y = sv.y * inv_sn;
        muv.z = sv.z * inv_sn; muv.w = sv.w * inv_sn;
        mu0 = ws[0] * invN * inv_sn;
    }
    float4 smu = muv;
    if (g == 0) smu.x = -smu.x;  // Lorentz sign folded into mu fragment

    // ---------------- pass 2: var (descending: reuse freshest L3 lines first) ----
    {
        float dacc0 = 0.f, dacc1 = 0.f;
        #pragma unroll 2
        for (int k = 0; k < FNITER; k += 2) {
            const size_t r0 = (size_t)gid0 + (size_t)(FNITER - 1 - k) * FRPS;
            const size_t r1 = (size_t)gid0 + (size_t)(FNITER - 2 - k) * FRPS;
            const float4 v0 = *(const float4*)(x + r0 * C + g * 4);
            const float4 v1 = *(const float4*)(x + r1 * C + g * 4);
            float p0 = fmaf(v0.x, smu.x, fmaf(v0.y, smu.y, fmaf(v0.z, smu.z, v0.w * smu.w)));
            float p1 = fmaf(v1.x, smu.x, fmaf(v1.y, smu.y, fmaf(v1.z, smu.z, v1.w * smu.w)));
            p0 = row16_sum(p0);
            p1 = row16_sum(p1);
            const float al0 = fmaxf(-p0, 1.0f + ACOSH_EPS);
            const float al1 = fmaxf(-p1, 1.0f + ACOSH_EPS);
            const float t0 = fmaf(al0, al0, -1.0f);
            const float t1 = fmaf(al1, al1, -1.0f);
            const float d0 = __logf(al0 + sqrtf(t0));
            const float d1 = __logf(al1 + sqrtf(t1));
            dacc0 = fmaf(d0, d0, dacc0);
            dacc1 = fmaf(d1, d1, dacc1);
        }
        float dacc = dacc0 + dacc1;
        dacc = row16_sum(dacc);
        dacc += __shfl_xor(dacc, 16, 64);
        dacc += __shfl_xor(dacc, 32, 64);
        if (lane == 0) wsum[wave] = dacc;
        __syncthreads();
        if (tid == 0)
            atomicAdd(&ws[128], (wsum[0] + wsum[1] + wsum[2] + wsum[3]) * (1.0f / 16.0f));
    }
    __threadfence();
    gg.sync();

    // ---------------- pass 3: output (ascending; nt stores keep x in L3) ----
    {
        const float4 bev = *(const float4*)(beta + g * 4);
        float4 sbe = bev;
        if (g == 0) sbe.x = -sbe.x;
        const float e0 = (g == 0) ? 1.0f : 0.0f;
        const float beta0 = beta[0];
        const float var = ws[128] * invN;
        const float divv = sqrtf(var + EPS);
        const float gscale = gamma[0] / divv;
        const float inv_dmo = 1.0f / (1.0f + mu0);
        const float inv_dob = 1.0f / (1.0f + beta0);
        for (int k = 0; k < FNITER; ++k) {
            const size_t r = (size_t)gid0 + (size_t)k * FRPS;
            const float4 xv = *(const float4*)(x + r * C + g * 4);
            float p = fmaf(xv.x, smu.x, fmaf(xv.y, smu.y, fmaf(xv.z, smu.z, xv.w * smu.w)));
            float x0m = (g == 0) ? xv.x : 0.0f;
            p = row16_sum(p);
            const float x0 = row16_sum(x0m);
            const float alpha = fmaxf(-p, 1.0f + ACOSH_EPS);
            const float t = fmaf(alpha, alpha, -1.0f);
            const float sq = sqrtf(t);
            const float d = __logf(alpha + sq);                // arccosh
            const float f = d * rsqrtf(fmaxf(t, ACOSH_EPS));   // d / sqrt(clip)
            float4 v;
            v.x = f * fmaf(-alpha, muv.x, xv.x);
            v.y = f * fmaf(-alpha, muv.y, xv.y);
            v.z = f * fmaf(-alpha, muv.z, xv.z);
            v.w = f * fmaf(-alpha, muv.w, xv.w);
            const float v0 = f * fmaf(-alpha, mu0, x0);        // v[0] without broadcast
            const float c1 = -v0 * inv_dmo;
            v.x = fmaf(c1, muv.x + e0, v.x);
            v.y = fmaf(c1, muv.y, v.y);
            v.z = fmaf(c1, muv.z, v.z);
            v.w = fmaf(c1, muv.w, v.w);
            v.x *= gscale; v.y *= gscale; v.z *= gscale; v.w *= gscale;
            float bv = fmaf(v.x, sbe.x, fmaf(v.y, sbe.y, fmaf(v.z, sbe.z, v.w * sbe.w)));
            bv = row16_sum(bv);
            const float c2 = bv * inv_dob;
            v.x = fmaf(c2, bev.x + e0, v.x);
            v.y = fmaf(c2, bev.y, v.y);
            v.z = fmaf(c2, bev.z, v.z);
            v.w = fmaf(c2, bev.w, v.w);
            const float svx = (g == 0) ? -v.x : v.x;
            float nn = fmaf(v.x, svx, fmaf(v.y, v.y, fmaf(v.z, v.z, v.w * v.w)));
            nn = row16_sum(nn);
            const float vn = sqrtf(fmaxf(nn, 1e-9f));
            const float e = __expf(vn);
            const float ei = __builtin_amdgcn_rcpf(e);
            const float ch = 0.5f * (e + ei);
            const float sc = 0.5f * (e - ei) * __builtin_amdgcn_rcpf(vn);
            float4 o;
            o.x = fmaf(sc, v.x, ch * bev.x);
            o.y = fmaf(sc, v.y, ch * bev.y);
            o.z = fmaf(sc, v.z, ch * bev.z);
            o.w = fmaf(sc, v.w, ch * bev.w);
            // non-temporal: don't let out-writes evict the L3-resident x
            __builtin_nontemporal_store(*(const f4*)&o, (f4*)(out + r * C + g * 4));
        }
    }
}

// ===================== fallback: original proven 4-kernel path =====================
__global__ __launch_bounds__(BLOCK) void colsum_kernel(
    const float* __restrict__ x, float* __restrict__ ws) {
    const int tid = threadIdx.x;
    const int g = tid & 15;
    const int gid0 = (blockIdx.x * BLOCK + tid) >> 4;
    const float* p = x + (size_t)gid0 * C + g * 4;
    float4 a0 = {0, 0, 0, 0}, a1 = {0, 0, 0, 0}, a2 = {0, 0, 0, 0}, a3 = {0, 0, 0, 0};
    #pragma unroll
    for (int k = 0; k < NITER; k += 4) {
        const float4 v0 = *(const float4*)(p + (size_t)(k + 0) * GPT * C);
        const float4 v1 = *(const float4*)(p + (size_t)(k + 1) * GPT * C);
        const float4 v2 = *(const float4*)(p + (size_t)(k + 2) * GPT * C);
        const float4 v3 = *(const float4*)(p + (size_t)(k + 3) * GPT * C);
        a0.x += v0.x; a0.y += v0.y; a0.z += v0.z; a0.w += v0.w;
        a1.x += v1.x; a1.y += v1.y; a1.z += v1.z; a1.w += v1.w;
        a2.x += v2.x; a2.y += v2.y; a2.z += v2.z; a2.w += v2.w;
        a3.x += v3.x; a3.y += v3.y; a3.z += v3.z; a3.w += v3.w;
    }
    float4 acc;
    acc.x = (a0.x + a1.x) + (a2.x + a3.x);
    acc.y = (a0.y + a1.y) + (a2.y + a3.y);
    acc.z = (a0.z + a1.z) + (a2.z + a3.z);
    acc.w = (a0.w + a1.w) + (a2.w + a3.w);
    #pragma unroll
    for (int m = 16; m <= 32; m <<= 1) {
        acc.x += __shfl_xor(acc.x, m, 64);
        acc.y += __shfl_xor(acc.y, m, 64);
        acc.z += __shfl_xor(acc.z, m, 64);
        acc.w += __shfl_xor(acc.w, m, 64);
    }
    __shared__ float lsum[4][64];
    const int wave = tid >> 6, lane = tid & 63;
    if (lane < 16) {
        lsum[wave][lane * 4 + 0] = acc.x;
        lsum[wave][lane * 4 + 1] = acc.y;
        lsum[wave][lane * 4 + 2] = acc.z;
        lsum[wave][lane * 4 + 3] = acc.w;
    }
    __syncthreads();
    if (tid < 64) {
        const float s = lsum[0][tid] + lsum[1][tid] + lsum[2][tid] + lsum[3][tid];
        atomicAdd(&ws[tid], s);
    }
}

__global__ void mu_kernel(float* __restrict__ ws) {
    const int j = threadIdx.x;  // 64 threads
    const float s = ws[j] * (1.0f / (float)NROWS);
    float p = s * s;
    if (j == 0) p = -p;
    #pragma unroll
    for (int m = 1; m < 64; m <<= 1) p += __shfl_xor(p, m, 64);
    const float sn = sqrtf(fmaxf(-p, 1e-9f));
    ws[64 + j] = s / sn;
}

__global__ __launch_bounds__(BLOCK) void var_kernel(
    const float* __restrict__ x, float* __restrict__ ws) {
    const int tid = threadIdx.x;
    const int g = tid & 15;
    const int gid0 = (blockIdx.x * BLOCK + tid) >> 4;
    float4 smu = *(const float4*)(ws + 64 + g * 4);
    if (g == 0) smu.x = -smu.x;
    float dacc = 0.f;
    #pragma unroll 8
    for (int k = 0; k < NITER; ++k) {
        const size_t r = (size_t)gid0 + (size_t)(NITER - 1 - k) * GPT;
        const float4 v = *(const float4*)(x + r * C + g * 4);
        float p = fmaf(v.x, smu.x, fmaf(v.y, smu.y, fmaf(v.z, smu.z, v.w * smu.w)));
        p = row16_sum(p);
        const float alpha = fmaxf(-p, 1.0f + ACOSH_EPS);
        const float t = fmaf(alpha, alpha, -1.0f);
        const float d = __logf(alpha + sqrtf(t));
        dacc = fmaf(d, d, dacc);
    }
    dacc = row16_sum(dacc);
    dacc += __shfl_xor(dacc, 16, 64);
    dacc += __shfl_xor(dacc, 32, 64);
    __shared__ float wsum[4];
    const int wave = tid >> 6, lane = tid & 63;
    if (lane == 0) wsum[wave] = dacc;
    __syncthreads();
    if (tid == 0)
        atomicAdd(&ws[128], (wsum[0] + wsum[1] + wsum[2] + wsum[3]) * (1.0f / 16.0f));
}

__global__ __launch_bounds__(BLOCK) void out_kernel(
    const float* __restrict__ x, const float* __restrict__ gamma,
    const float* __restrict__ beta, float* __restrict__ out,
    const float* __restrict__ ws) {
    const int tid = threadIdx.x;
    const int g = tid & 15;
    const int gid0 = (blockIdx.x * BLOCK + tid) >> 4;
    const float4 muv = *(const float4*)(ws + 64 + g * 4);
    const float4 bev = *(const float4*)(beta + g * 4);
    float4 smu = muv, sbe = bev;
    if (g == 0) { smu.x = -smu.x; sbe.x = -sbe.x; }
    const float e0 = (g == 0) ? 1.0f : 0.0f;
    const float mu0 = ws[64];
    const float beta0 = beta[0];
    const float var = ws[128] * (1.0f / (float)NROWS);
    const float divv = sqrtf(var + EPS);
    const float gscale = gamma[0] / divv;
    const float inv_dmo = 1.0f / (1.0f + mu0);
    const float inv_dob = 1.0f / (1.0f + beta0);
    #pragma unroll 4
    for (int k = 0; k < NITER; ++k) {
        const size_t r = (size_t)gid0 + (size_t)k * GPT;
        const float4 xv = *(const float4*)(x + r * C + g * 4);
        float p = fmaf(xv.x, smu.x, fmaf(xv.y, smu.y, fmaf(xv.z, smu.z, xv.w * smu.w)));
        float x0m = (g == 0) ? xv.x : 0.0f;
        p = row16_sum(p);
        const float x0 = row16_sum(x0m);
        const float alpha = fmaxf(-p, 1.0f + ACOSH_EPS);
        const float t = fmaf(alpha, alpha, -1.0f);
        const float sq = sqrtf(t);
        const float d = __logf(alpha + sq);
        const float f = d * rsqrtf(fmaxf(t, ACOSH_EPS));
        float4 v;
        v.x = f * fmaf(-alpha, muv.x, xv.x);
        v.y = f * fmaf(-alpha, muv.y, xv.y);
        v.z = f * fmaf(-alpha, muv.z, xv.z);
        v.w = f * fmaf(-alpha, muv.w, xv.w);
        const float v0 = f * fmaf(-alpha, mu0, x0);
        const float c1 = -v0 * inv_dmo;
        v.x = fmaf(c1, muv.x + e0, v.x);
        v.y = fmaf(c1, muv.y, v.y);
        v.z = fmaf(c1, muv.z, v.z);
        v.w = fmaf(c1, muv.w, v.w);
        v.x *= gscale; v.y *= gscale; v.z *= gscale; v.w *= gscale;
        float bv = fmaf(v.x, sbe.x, fmaf(v.y, sbe.y, fmaf(v.z, sbe.z, v.w * sbe.w)));
        bv = row16_sum(bv);
        const float c2 = bv * inv_dob;
        v.x = fmaf(c2, bev.x + e0, v.x);
        v.y = fmaf(c2, bev.y, v.y);
        v.z = fmaf(c2, bev.z, v.z);
        v.w = fmaf(c2, bev.w, v.w);
        const float svx = (g == 0) ? -v.x : v.x;
        float nn = fmaf(v.x, svx, fmaf(v.y, v.y, fmaf(v.z, v.z, v.w * v.w)));
        nn = row16_sum(nn);
        const float vn = sqrtf(fmaxf(nn, 1e-9f));
        const float e = __expf(vn);
        const float ei = __builtin_amdgcn_rcpf(e);
        const float ch = 0.5f * (e + ei);
        const float sc = 0.5f * (e - ei) * __builtin_amdgcn_rcpf(vn);
        float4 o;
        o.x = fmaf(sc, v.x, ch * bev.x);
        o.y = fmaf(sc, v.y, ch * bev.y);
        o.z = fmaf(sc, v.z, ch * bev.z);
        o.w = fmaf(sc, v.w, ch * bev.w);
        *(float4*)(out + r * C + g * 4) = o;
    }
}

extern "C" void kernel_launch(void* const* d_in, const int* in_sizes, int n_in,
                              void* d_out, int out_size, void* d_ws, size_t ws_size,
                              hipStream_t stream) {
    const float* x = (const float*)d_in[0];
    const float* gamma = (const float*)d_in[1];
    const float* beta = (const float*)d_in[2];
    float* out = (float*)d_out;
    float* ws = (float*)d_ws;

    hipMemsetAsync(ws, 0, 129 * sizeof(float), stream);

    void* args[] = {(void*)&x, (void*)&gamma, (void*)&beta, (void*)&out, (void*)&ws};
    hipError_t err = hipLaunchCooperativeKernel((const void*)lbn_fused, dim3(FGRID),
                                                dim3(FBLOCK), args, 0, stream);
    if (err != hipSuccess) {
        // fallback: proven 4-kernel path
        colsum_kernel<<<GRID, BLOCK, 0, stream>>>(x, ws);
        mu_kernel<<<1, 64, 0, stream>>>(ws);
        var_kernel<<<GRID, BLOCK, 0, stream>>>(x, ws);
        out_kernel<<<GRID, BLOCK, 0, stream>>>(x, gamma, beta, out, ws);
    }
}

// Round 2
// 561.449 us; speedup vs baseline: 1.7914x; 1.7914x over previous
//
#include <hip/hip_runtime.h>
#include <math.h>

#define NROWS 1048576
#define C 64
#define GRID 4096
#define BLOCK 256
#define GPT ((GRID * BLOCK) / 16)   // row-groups covered per chunk = 65536
#define NITER (NROWS / GPT)         // 16 chunks

constexpr float EPS = 1e-5f;
constexpr float ACOSH_EPS = 1e-7f;

typedef float f4 __attribute__((ext_vector_type(4)));

// ws layout (floats):
//   [0:512]   col-sum replicas: 8 replicas x 64 cols (blockIdx&7 -> replica,
//             which matches XCD under round-robin dispatch -> line stays XCD-local)
//   [512:520] d2-sum replicas: 8 scalars
#define WS_D2 512

// Sum across the 16-lane DPP row via rotate-and-add: 4 VALU ops, no LDS pipe.
// Every lane ends with the full row-of-16 sum.
__device__ __forceinline__ float row16_sum(float x) {
    x += __int_as_float(__builtin_amdgcn_update_dpp(
        0, __float_as_int(x), 0x121, 0xF, 0xF, true));  // row_ror:1
    x += __int_as_float(__builtin_amdgcn_update_dpp(
        0, __float_as_int(x), 0x122, 0xF, 0xF, true));  // row_ror:2
    x += __int_as_float(__builtin_amdgcn_update_dpp(
        0, __float_as_int(x), 0x124, 0xF, 0xF, true));  // row_ror:4
    x += __int_as_float(__builtin_amdgcn_update_dpp(
        0, __float_as_int(x), 0x128, 0xF, 0xF, true));  // row_ror:8
    return x;
}

// Recompute mu from the 8 col-sum replicas, entirely in-register.
// Proven numerically equivalent in round 1 (fused kernel passed with this).
// Replica loads are uniform addresses -> scalar loads, L2-resident (516 B).
__device__ __forceinline__ void compute_mu(const float* __restrict__ ws, int g,
                                           float4& muv, float& mu0) {
    float4 sv = {0.f, 0.f, 0.f, 0.f};
    #pragma unroll
    for (int rep = 0; rep < 8; ++rep) {
        const float4 t = *(const float4*)(ws + rep * 64 + g * 4);
        sv.x += t.x; sv.y += t.y; sv.z += t.z; sv.w += t.w;
    }
    const float invN = 1.0f / (float)NROWS;
    sv.x *= invN; sv.y *= invN; sv.z *= invN; sv.w *= invN;
    float pp = fmaf(sv.y, sv.y, fmaf(sv.z, sv.z, sv.w * sv.w));
    pp = (g == 0) ? fmaf(-sv.x, sv.x, pp) : fmaf(sv.x, sv.x, pp);
    pp = row16_sum(pp);  // <s,s>_L broadcast to all 16 lanes of the group
    const float sn = sqrtf(fmaxf(-pp, 1e-9f));
    const float inv_sn = 1.0f / sn;
    muv.x = sv.x * inv_sn; muv.y = sv.y * inv_sn;
    muv.z = sv.z * inv_sn; muv.w = sv.w * inv_sn;
    float s0 = 0.f;
    #pragma unroll
    for (int rep = 0; rep < 8; ++rep) s0 += ws[rep * 64];
    mu0 = s0 * invN * inv_sn;
}

__global__ __launch_bounds__(BLOCK) void colsum_kernel(
    const float* __restrict__ x, float* __restrict__ ws) {
    const int tid = threadIdx.x;
    const int g = tid & 15;
    const int gid0 = (blockIdx.x * BLOCK + tid) >> 4;
    const float* p = x + (size_t)gid0 * C + g * 4;
    float4 a0 = {0, 0, 0, 0}, a1 = {0, 0, 0, 0}, a2 = {0, 0, 0, 0}, a3 = {0, 0, 0, 0};
    #pragma unroll
    for (int k = 0; k < NITER; k += 4) {
        // 4 independent loads in flight per round
        const float4 v0 = *(const float4*)(p + (size_t)(k + 0) * GPT * C);
        const float4 v1 = *(const float4*)(p + (size_t)(k + 1) * GPT * C);
        const float4 v2 = *(const float4*)(p + (size_t)(k + 2) * GPT * C);
        const float4 v3 = *(const float4*)(p + (size_t)(k + 3) * GPT * C);
        a0.x += v0.x; a0.y += v0.y; a0.z += v0.z; a0.w += v0.w;
        a1.x += v1.x; a1.y += v1.y; a1.z += v1.z; a1.w += v1.w;
        a2.x += v2.x; a2.y += v2.y; a2.z += v2.z; a2.w += v2.w;
        a3.x += v3.x; a3.y += v3.y; a3.z += v3.z; a3.w += v3.w;
    }
    float4 acc;
    acc.x = (a0.x + a1.x) + (a2.x + a3.x);
    acc.y = (a0.y + a1.y) + (a2.y + a3.y);
    acc.z = (a0.z + a1.z) + (a2.z + a3.z);
    acc.w = (a0.w + a1.w) + (a2.w + a3.w);
    // lanes l, l^16, l^32, l^48 hold the same column group
    #pragma unroll
    for (int m = 16; m <= 32; m <<= 1) {
        acc.x += __shfl_xor(acc.x, m, 64);
        acc.y += __shfl_xor(acc.y, m, 64);
        acc.z += __shfl_xor(acc.z, m, 64);
        acc.w += __shfl_xor(acc.w, m, 64);
    }
    __shared__ float lsum[4][64];
    const int wave = tid >> 6, lane = tid & 63;
    if (lane < 16) {
        lsum[wave][lane * 4 + 0] = acc.x;
        lsum[wave][lane * 4 + 1] = acc.y;
        lsum[wave][lane * 4 + 2] = acc.z;
        lsum[wave][lane * 4 + 3] = acc.w;
    }
    __syncthreads();
    if (tid < 64) {
        const float s = lsum[0][tid] + lsum[1][tid] + lsum[2][tid] + lsum[3][tid];
        // 8-way replicated target: contention per address 4096 -> 512,
        // and replica == XCD under round-robin dispatch.
        atomicAdd(&ws[(blockIdx.x & 7) * 64 + tid], s);
    }
}

__global__ __launch_bounds__(BLOCK) void var_kernel(
    const float* __restrict__ x, float* __restrict__ ws) {
    const int tid = threadIdx.x;
    const int g = tid & 15;
    const int gid0 = (blockIdx.x * BLOCK + tid) >> 4;
    float4 muv; float mu0;
    compute_mu(ws, g, muv, mu0);  // mu0 unused here (dead, folds away)
    float4 smu = muv;
    if (g == 0) smu.x = -smu.x;  // Lorentz sign folded into the mu fragment
    float dacc = 0.f;
    // descending chunk order: re-reads colsum's freshest L3-resident lines first
    #pragma unroll 8
    for (int k = 0; k < NITER; ++k) {
        const size_t r = (size_t)gid0 + (size_t)(NITER - 1 - k) * GPT;
        const float4 v = *(const float4*)(x + r * C + g * 4);
        float p = fmaf(v.x, smu.x, fmaf(v.y, smu.y, fmaf(v.z, smu.z, v.w * smu.w)));
        p = row16_sum(p);
        const float alpha = fmaxf(-p, 1.0f + ACOSH_EPS);
        const float t = fmaf(alpha, alpha, -1.0f);
        const float d = __logf(alpha + sqrtf(t));
        dacc = fmaf(d, d, dacc);  // every lane counts; scale by 1/16 at the end
    }
    dacc = row16_sum(dacc);
    dacc += __shfl_xor(dacc, 16, 64);
    dacc += __shfl_xor(dacc, 32, 64);
    __shared__ float wsum[4];
    const int wave = tid >> 6, lane = tid & 63;
    if (lane == 0) wsum[wave] = dacc;
    __syncthreads();
    if (tid == 0)
        atomicAdd(&ws[WS_D2 + (blockIdx.x & 7)],
                  (wsum[0] + wsum[1] + wsum[2] + wsum[3]) * (1.0f / 16.0f));
}

__global__ __launch_bounds__(BLOCK) void out_kernel(
    const float* __restrict__ x, const float* __restrict__ gamma,
    const float* __restrict__ beta, float* __restrict__ out,
    const float* __restrict__ ws) {
    const int tid = threadIdx.x;
    const int g = tid & 15;
    const int gid0 = (blockIdx.x * BLOCK + tid) >> 4;
    float4 muv; float mu0;
    compute_mu(ws, g, muv, mu0);
    const float4 bev = *(const float4*)(beta + g * 4);
    float4 smu = muv, sbe = bev;
    if (g == 0) { smu.x = -smu.x; sbe.x = -sbe.x; }
    const float e0 = (g == 0) ? 1.0f : 0.0f;  // o-vector lives in lane g==0 slot .x
    const float beta0 = beta[0];
    float d2 = 0.f;
    #pragma unroll
    for (int rep = 0; rep < 8; ++rep) d2 += ws[WS_D2 + rep];
    const float var = d2 * (1.0f / (float)NROWS);
    const float divv = sqrtf(var + EPS);
    const float gscale = gamma[0] / divv;
    const float inv_dmo = 1.0f / (1.0f + mu0);
    const float inv_dob = 1.0f / (1.0f + beta0);
    #pragma unroll 4
    for (int k = 0; k < NITER; ++k) {
        const size_t r = (size_t)gid0 + (size_t)k * GPT;  // ascending = reverse of var
        const float4 xv = *(const float4*)(x + r * C + g * 4);
        // alpha = clip(-<x,mu>_L, 1+eps); x0 recovered via masked rotate-reduce
        float p = fmaf(xv.x, smu.x, fmaf(xv.y, smu.y, fmaf(xv.z, smu.z, xv.w * smu.w)));
        float x0m = (g == 0) ? xv.x : 0.0f;
        p = row16_sum(p);
        const float x0 = row16_sum(x0m);
        const float alpha = fmaxf(-p, 1.0f + ACOSH_EPS);
        const float t = fmaf(alpha, alpha, -1.0f);
        const float sq = sqrtf(t);
        const float d = __logf(alpha + sq);                 // arccosh
        const float f = d * rsqrtf(fmaxf(t, ACOSH_EPS));    // d / sqrt(clip)
        float4 v;
        v.x = f * fmaf(-alpha, muv.x, xv.x);
        v.y = f * fmaf(-alpha, muv.y, xv.y);
        v.z = f * fmaf(-alpha, muv.z, xv.z);
        v.w = f * fmaf(-alpha, muv.w, xv.w);
        // ov = -v[0] without a broadcast: v0 = f*(x0 - alpha*mu0)
        const float v0 = f * fmaf(-alpha, mu0, x0);
        const float c1 = -v0 * inv_dmo;
        v.x = fmaf(c1, muv.x + e0, v.x);
        v.y = fmaf(c1, muv.y, v.y);
        v.z = fmaf(c1, muv.z, v.z);
        v.w = fmaf(c1, muv.w, v.w);
        v.x *= gscale; v.y *= gscale; v.z *= gscale; v.w *= gscale;
        // bv = <beta, v>_L
        float bv = fmaf(v.x, sbe.x, fmaf(v.y, sbe.y, fmaf(v.z, sbe.z, v.w * sbe.w)));
        bv = row16_sum(bv);
        const float c2 = bv * inv_dob;
        v.x = fmaf(c2, bev.x + e0, v.x);
        v.y = fmaf(c2, bev.y, v.y);
        v.z = fmaf(c2, bev.z, v.z);
        v.w = fmaf(c2, bev.w, v.w);
        // vn = sqrt(clip(<v,v>_L)); out = cosh(vn)*beta + sinh(vn)/vn * v
        const float svx = (g == 0) ? -v.x : v.x;
        float nn = fmaf(v.x, svx, fmaf(v.y, v.y, fmaf(v.z, v.z, v.w * v.w)));
        nn = row16_sum(nn);
        const float vn = sqrtf(fmaxf(nn, 1e-9f));
        const float e = __expf(vn);
        const float ei = __builtin_amdgcn_rcpf(e);
        const float ch = 0.5f * (e + ei);
        const float sc = 0.5f * (e - ei) * __builtin_amdgcn_rcpf(vn);
        float4 o;
        o.x = fmaf(sc, v.x, ch * bev.x);
        o.y = fmaf(sc, v.y, ch * bev.y);
        o.z = fmaf(sc, v.z, ch * bev.z);
        o.w = fmaf(sc, v.w, ch * bev.w);
        // non-temporal: out is never re-read — don't let it evict L3-resident x
        // (round 1 measured the eviction: ~115 MB extra HBM fetch without this)
        __builtin_nontemporal_store(*(const f4*)&o, (f4*)(out + r * C + g * 4));
    }
}

extern "C" void kernel_launch(void* const* d_in, const int* in_sizes, int n_in,
                              void* d_out, int out_size, void* d_ws, size_t ws_size,
                              hipStream_t stream) {
    const float* x = (const float*)d_in[0];
    const float* gamma = (const float*)d_in[1];
    const float* beta = (const float*)d_in[2];
    float* out = (float*)d_out;
    float* ws = (float*)d_ws;

    hipMemsetAsync(ws, 0, 520 * sizeof(float), stream);
    colsum_kernel<<<GRID, BLOCK, 0, stream>>>(x, ws);
    var_kernel<<<GRID, BLOCK, 0, stream>>>(x, ws);
    out_kernel<<<GRID, BLOCK, 0, stream>>>(x, gamma, beta, out, ws);
}